// Round 1
// baseline (725.788 us; speedup 1.0000x reference)
//
#include <hip/hip_runtime.h>
#include <hip/hip_bf16.h>

#define B_SZ 4096
#define DDIM 16384
#define HDIM 256
#define NQ 8

typedef __attribute__((ext_vector_type(8))) short bf16x8;
typedef __attribute__((ext_vector_type(4))) short s16x4;
typedef __attribute__((ext_vector_type(4))) float f32x4;

__device__ inline short f2bf(float f) {
    union { float f; unsigned u; } v; v.f = f;
    unsigned r = v.u + 0x7fffu + ((v.u >> 16) & 1u);
    return (short)(r >> 16);
}
__device__ inline float lrelu(float x) { return x >= 0.f ? x : 0.2f * x; }

__device__ inline float2 cmul(float2 a, float2 b) {
    return make_float2(a.x * b.x - a.y * b.y, a.x * b.y + a.y * b.x);
}
__device__ inline float2 cadd(float2 a, float2 b) {
    return make_float2(a.x + b.x, a.y + b.y);
}

// ---------------------------------------------------------------------------
// GEMM:  C[M x 256] = A[M x K] * Bw[256 x K]^T   (bf16 MFMA, f32 accumulate)
// BM=128, BN=256 (full), BK=64, 512 threads (8 waves, 16 rows each).
// PRE:   apply leaky(a + preBias[k]) to A elements while staging (for GEMM2).
// ATOMIC: atomicAdd partials into C (split-K).  else: C = leaky(acc + postBias).
// LDS XOR swizzle (row&7)<<4 on byte offsets: rows are 128B -> fixes the
// 32-way bank conflict on ds_read_b128 column slices.
// ---------------------------------------------------------------------------
template<bool PRE, bool ATOMIC>
__global__ __launch_bounds__(512) void gemm_bt(
    const float* __restrict__ A, const float* __restrict__ Bw,
    const float* __restrict__ preBias, const float* __restrict__ postBias,
    float* __restrict__ C, int K, int kchunk)
{
    __shared__ char smem[128 * 128 + 256 * 128];   // A tile 16KB + B tile 32KB
    char* aT = smem;
    char* bT = smem + 128 * 128;

    const int m0 = blockIdx.x * 128;
    const int kbase = blockIdx.y * kchunk;
    const int t = threadIdx.x;
    const int lane = t & 63;
    const int w = t >> 6;

    f32x4 acc[16];
#pragma unroll
    for (int i = 0; i < 16; i++) acc[i] = (f32x4){0.f, 0.f, 0.f, 0.f};

    for (int kk = kbase; kk < kbase + kchunk; kk += 64) {
        // ---- stage A: 128x64 f32 -> bf16 (2048 float4, 4/thread) ----
#pragma unroll
        for (int i = 0; i < 4; i++) {
            int f = t + i * 512;
            int row = f >> 4, c4 = f & 15;
            float4 v = *(const float4*)(A + (size_t)(m0 + row) * K + kk + c4 * 4);
            if (PRE) {
                int kg = kk + c4 * 4;
                v.x = lrelu(v.x + preBias[kg + 0]);
                v.y = lrelu(v.y + preBias[kg + 1]);
                v.z = lrelu(v.z + preBias[kg + 2]);
                v.w = lrelu(v.w + preBias[kg + 3]);
            }
            s16x4 h = (s16x4){f2bf(v.x), f2bf(v.y), f2bf(v.z), f2bf(v.w)};
            int byte = row * 128 + c4 * 8;
            *(s16x4*)(aT + (byte ^ ((row & 7) << 4))) = h;
        }
        // ---- stage B: 256x64 f32 -> bf16 (4096 float4, 8/thread) ----
#pragma unroll
        for (int i = 0; i < 8; i++) {
            int f = t + i * 512;
            int row = f >> 4, c4 = f & 15;
            float4 v = *(const float4*)(Bw + (size_t)row * K + kk + c4 * 4);
            s16x4 h = (s16x4){f2bf(v.x), f2bf(v.y), f2bf(v.z), f2bf(v.w)};
            int byte = row * 128 + c4 * 8;
            *(s16x4*)(bT + (byte ^ ((row & 7) << 4))) = h;
        }
        __syncthreads();

        const int am0 = w * 16;
#pragma unroll
        for (int ks = 0; ks < 2; ks++) {
            int k0 = ks * 32 + (lane >> 4) * 8;      // bf16 index in row
            int arow = am0 + (lane & 15);
            bf16x8 af = *(bf16x8*)(aT + ((arow * 128 + k0 * 2) ^ ((arow & 7) << 4)));
#pragma unroll
            for (int nf = 0; nf < 16; nf++) {
                int nrow = nf * 16 + (lane & 15);
                bf16x8 bfr = *(bf16x8*)(bT + ((nrow * 128 + k0 * 2) ^ ((nrow & 7) << 4)));
                acc[nf] = __builtin_amdgcn_mfma_f32_16x16x32_bf16(af, bfr, acc[nf], 0, 0, 0);
            }
        }
        __syncthreads();
    }

    // ---- epilogue: C/D layout col=lane&15, row=(lane>>4)*4+r ----
#pragma unroll
    for (int nf = 0; nf < 16; nf++) {
        int col = nf * 16 + (lane & 15);
#pragma unroll
        for (int r = 0; r < 4; r++) {
            int row = m0 + w * 16 + (lane >> 4) * 4 + r;
            if (ATOMIC) {
                atomicAdd(&C[(size_t)row * 256 + col], acc[nf][r]);
            } else {
                float v = acc[nf][r] + postBias[col];
                C[(size_t)row * 256 + col] = lrelu(v);
            }
        }
    }
}

// ---------------------------------------------------------------------------
// q_in = h2 @ W3^T + b3 ; angles = (q_in + 1) * pi/2
// ---------------------------------------------------------------------------
__global__ __launch_bounds__(256) void qin_kernel(
    const float* __restrict__ h2, const float* __restrict__ W3,
    const float* __restrict__ b3, float* __restrict__ angles)
{
    int gid = blockIdx.x * 256 + threadIdx.x;
    int b = gid >> 3, q = gid & 7;
    const float* hr = h2 + (size_t)b * 256;
    const float* wr = W3 + q * 256;
    float s = b3[q];
#pragma unroll 8
    for (int k = 0; k < 256; k++) s += hr[k] * wr[k];
    angles[gid] = (s + 1.0f) * 1.5707963267948966f;
}

// ---------------------------------------------------------------------------
// Precompute fused U = Rz*Ry*Rx for each (layer, qubit): batch-independent.
// ---------------------------------------------------------------------------
__global__ void qprep(const float* __restrict__ qp, float* __restrict__ U)
{
    int g = threadIdx.x;
    if (g >= 16) return;
    float ax = qp[g * 3 + 0], ay = qp[g * 3 + 1], az = qp[g * 3 + 2];
    float sa, ca, sb, cb, sg, cg;
    sincosf(ax * 0.5f, &sa, &ca);
    sincosf(ay * 0.5f, &sb, &cb);
    sincosf(az * 0.5f, &sg, &cg);
    // M = Ry @ Rx
    float2 M00 = make_float2(cb * ca,  sb * sa);
    float2 M01 = make_float2(-sb * ca, -cb * sa);
    float2 M10 = make_float2(sb * ca,  -cb * sa);
    float2 M11 = make_float2(cb * ca,  -sb * sa);
    float2 e0 = make_float2(cg, -sg);   // e^{-i g/2}
    float2 e1 = make_float2(cg,  sg);   // e^{+i g/2}
    float2* out = (float2*)(U + g * 8);
    out[0] = cmul(e0, M00);
    out[1] = cmul(e0, M01);
    out[2] = cmul(e1, M10);
    out[3] = cmul(e1, M11);
}

// ---------------------------------------------------------------------------
// 8-qubit statevector sim: 1 block / batch row, 256 threads = 1 amp each.
// Qubit q <-> bit (7-q) of the amplitude index. Ping-pong LDS, 1 barrier/gate.
// ---------------------------------------------------------------------------
__global__ __launch_bounds__(256) void qsim(
    const float* __restrict__ angles, const float* __restrict__ Ug,
    float* __restrict__ qf)
{
    int b = blockIdx.x, i = threadIdx.x;
    __shared__ float2 st[2][256];
    __shared__ float red[8][4];

    // initial product state: RX(angle_q) applied to |0...0>
    float2 amp = make_float2(1.f, 0.f);
#pragma unroll
    for (int q = 0; q < 8; q++) {
        float tq = angles[(size_t)b * 8 + q];
        float s, c;
        sincosf(tq * 0.5f, &s, &c);
        if ((i >> (7 - q)) & 1)
            amp = make_float2(amp.y * s, -amp.x * s);   // * (0, -s)
        else
            amp = make_float2(amp.x * c, amp.y * c);    // * (c, 0)
    }
    int cur = 0;
    st[0][i] = amp;
    __syncthreads();

#pragma unroll
    for (int l = 0; l < 2; l++) {
#pragma unroll
        for (int q = 0; q < 8; q++) {
            const float2* U = (const float2*)(Ug + (l * 8 + q) * 8);
            int sh = 7 - q, s = 1 << sh, bit = (i >> sh) & 1;
            float2 a0 = st[cur][i & ~s];
            float2 a1 = st[cur][i |  s];
            float2 u0 = U[bit * 2 + 0];
            float2 u1 = U[bit * 2 + 1];
            float2 r = cadd(cmul(u0, a0), cmul(u1, a1));
            st[cur ^ 1][i] = r;
            __syncthreads();
            cur ^= 1;
        }
#pragma unroll
        for (int q = 0; q < 7; q++) {       // CNOT(q, q+1)
            int sc = 1 << (7 - q), stt = 1 << (7 - (q + 1));
            int j = (i & sc) ? (i ^ stt) : i;
            float2 r = st[cur][j];
            st[cur ^ 1][i] = r;
            __syncthreads();
            cur ^= 1;
        }
    }

    float2 a = st[cur][i];
    float p = a.x * a.x + a.y * a.y;
    int lane = i & 63, wv = i >> 6;
#pragma unroll
    for (int q = 0; q < 8; q++) {
        float v = ((i >> (7 - q)) & 1) ? -p : p;
#pragma unroll
        for (int off = 32; off > 0; off >>= 1) v += __shfl_xor(v, off, 64);
        if (lane == 0) red[q][wv] = v;
    }
    __syncthreads();
    if (i < 8) qf[(size_t)b * 8 + i] = red[i][0] + red[i][1] + red[i][2] + red[i][3];
}

// ---------------------------------------------------------------------------
// Head MLP: comb[14] -> 256 -> 128 -> 1.  1 block / batch row.
// ---------------------------------------------------------------------------
__global__ __launch_bounds__(256) void head(
    const float* __restrict__ qf, const int* __restrict__ cid,
    const float* __restrict__ emb,
    const float* __restrict__ W4, const float* __restrict__ b4,
    const float* __restrict__ W5, const float* __restrict__ b5,
    const float* __restrict__ W6, const float* __restrict__ b6,
    float* __restrict__ out)
{
    int b = blockIdx.x, t = threadIdx.x;
    __shared__ float comb[16];
    __shared__ float h3[256];
    __shared__ float h4[128];

    if (t < 8) comb[t] = qf[(size_t)b * 8 + t];
    else if (t < 14) comb[t] = emb[cid[b] * 6 + (t - 8)];
    __syncthreads();

    float s = b4[t];
    const float* w4r = W4 + t * 14;
#pragma unroll
    for (int i = 0; i < 14; i++) s += comb[i] * w4r[i];
    h3[t] = lrelu(s);
    __syncthreads();

    if (t < 128) {
        float s2 = b5[t];
        const float* w5r = W5 + t * 256;
#pragma unroll 8
        for (int i = 0; i < 256; i++) s2 += h3[i] * w5r[i];
        h4[t] = lrelu(s2);
    }
    __syncthreads();

    if (t < 64) {
        float v = h4[t] * W6[t] + h4[t + 64] * W6[t + 64];
#pragma unroll
        for (int off = 32; off > 0; off >>= 1) v += __shfl_xor(v, off, 64);
        if (t == 0) out[b] = v + b6[0];
    }
}

extern "C" void kernel_launch(void* const* d_in, const int* in_sizes, int n_in,
                              void* d_out, int out_size, void* d_ws, size_t ws_size,
                              hipStream_t stream)
{
    const float* img = (const float*)d_in[0];
    const int*   cid = (const int*)d_in[1];
    const float* W1  = (const float*)d_in[2];
    const float* b1  = (const float*)d_in[3];
    const float* W2  = (const float*)d_in[4];
    const float* b2  = (const float*)d_in[5];
    const float* W3  = (const float*)d_in[6];
    const float* b3  = (const float*)d_in[7];
    const float* qp  = (const float*)d_in[8];
    const float* emb = (const float*)d_in[9];
    const float* W4  = (const float*)d_in[10];
    const float* b4  = (const float*)d_in[11];
    const float* W5  = (const float*)d_in[12];
    const float* b5  = (const float*)d_in[13];
    const float* W6  = (const float*)d_in[14];
    const float* b6  = (const float*)d_in[15];

    float* h1     = (float*)d_ws;                       // 4096*256
    float* h2     = h1 + (size_t)B_SZ * HDIM;           // 4096*256
    float* angles = h2 + (size_t)B_SZ * HDIM;           // 4096*8
    float* qfbuf  = angles + (size_t)B_SZ * NQ;         // 4096*8
    float* Umat   = qfbuf + (size_t)B_SZ * NQ;          // 16*8

    hipMemsetAsync(h1, 0, (size_t)B_SZ * HDIM * sizeof(float), stream);

    // GEMM1: h1 += img @ W1^T   (split-K=8, atomics)
    gemm_bt<false, true><<<dim3(32, 8), 512, 0, stream>>>(
        img, W1, nullptr, nullptr, h1, DDIM, DDIM / 8);

    // GEMM2: h2 = leaky(leaky(h1+b1) @ W2^T + b2)
    gemm_bt<true, false><<<dim3(32, 1), 512, 0, stream>>>(
        h1, W2, b1, b2, h2, HDIM, HDIM);

    qin_kernel<<<B_SZ * NQ / 256, 256, 0, stream>>>(h2, W3, b3, angles);
    qprep<<<1, 64, 0, stream>>>(qp, Umat);
    qsim<<<B_SZ, 256, 0, stream>>>(angles, Umat, qfbuf);
    head<<<B_SZ, 256, 0, stream>>>(qfbuf, cid, emb, W4, b4, W5, b5, W6, b6,
                                   (float*)d_out);
}

// Round 2
// 508.890 us; speedup vs baseline: 1.4262x; 1.4262x over previous
//
#include <hip/hip_runtime.h>
#include <hip/hip_bf16.h>

#define B_SZ 4096
#define DDIM 16384
#define HDIM 256
#define NQ 8

typedef __attribute__((ext_vector_type(8))) short bf16x8;
typedef __attribute__((ext_vector_type(4))) short s16x4;
typedef __attribute__((ext_vector_type(4))) float f32x4;

__device__ inline short f2bf(float f) {
    union { float f; unsigned u; } v; v.f = f;
    unsigned r = v.u + 0x7fffu + ((v.u >> 16) & 1u);
    return (short)(r >> 16);
}
__device__ inline float bf2f(short h) {
    union { unsigned u; float f; } v; v.u = ((unsigned)(unsigned short)h) << 16;
    return v.f;
}
__device__ inline float lrelu(float x) { return x >= 0.f ? x : 0.2f * x; }

__device__ inline float2 cmul(float2 a, float2 b) {
    return make_float2(a.x * b.x - a.y * b.y, a.x * b.y + a.y * b.x);
}
__device__ inline float2 cadd(float2 a, float2 b) {
    return make_float2(a.x + b.x, a.y + b.y);
}

// hi/lo bf16 split of 8 f32: a + b -> two bf16x8 fragments (compensated)
__device__ inline void mk_hilo(float4 a, float4 b, bf16x8& hi, bf16x8& lo) {
    float xs[8] = {a.x, a.y, a.z, a.w, b.x, b.y, b.z, b.w};
#pragma unroll
    for (int j = 0; j < 8; j++) {
        short h = f2bf(xs[j]);
        hi[j] = h;
        lo[j] = f2bf(xs[j] - bf2f(h));
    }
}

// ---------------------------------------------------------------------------
// GEMM: C[4096 x 256] = A[4096 x K] * Bw[256 x K]^T  (bf16 MFMA, f32 acc)
// BM=128, BN=256, BK=64, 512 threads. Register-double-buffered prefetch.
// NSPLIT>1: split-K, y=bid%NSPLIT (XCD-pinned chunk), store f32 partials.
// else: C = lrelu(acc + postBias).
// ---------------------------------------------------------------------------
template<int NSPLIT, bool PART>
__global__ __launch_bounds__(512, 2) void gemm_bt(
    const float* __restrict__ A, const float* __restrict__ Bw,
    const float* __restrict__ postBias, float* __restrict__ C, int K)
{
    __shared__ char smem[128 * 128 + 256 * 128];
    char* aT = smem;
    char* bT = smem + 128 * 128;

    const int bid = blockIdx.x;
    const int y = bid % NSPLIT;
    const int x = bid / NSPLIT;
    const int kchunk = K / NSPLIT;
    const int kbase = y * kchunk;
    const int m0 = x * 128;
    const int t = threadIdx.x;
    const int lane = t & 63;
    const int w = t >> 6;
    const int arow = t >> 4, ac4 = t & 15;

    f32x4 acc[16];
#pragma unroll
    for (int i = 0; i < 16; i++) acc[i] = (f32x4){0.f, 0.f, 0.f, 0.f};

    float4 avA[4], bvA[8], avB[4], bvB[8];

    auto loadT = [&](int kk, float4* av, float4* bv) {
#pragma unroll
        for (int i = 0; i < 4; i++)
            av[i] = *(const float4*)(A + (size_t)(m0 + arow + 32 * i) * K + kk + ac4 * 4);
#pragma unroll
        for (int i = 0; i < 8; i++)
            bv[i] = *(const float4*)(Bw + (size_t)(arow + 32 * i) * K + kk + ac4 * 4);
    };
    auto stash = [&](float4* av, float4* bv) {
#pragma unroll
        for (int i = 0; i < 4; i++) {
            int row = arow + 32 * i;
            float4 v = av[i];
            s16x4 h = (s16x4){f2bf(v.x), f2bf(v.y), f2bf(v.z), f2bf(v.w)};
            int byte = row * 128 + ac4 * 8;
            *(s16x4*)(aT + (byte ^ ((row & 7) << 4))) = h;
        }
#pragma unroll
        for (int i = 0; i < 8; i++) {
            int row = arow + 32 * i;
            float4 v = bv[i];
            s16x4 h = (s16x4){f2bf(v.x), f2bf(v.y), f2bf(v.z), f2bf(v.w)};
            int byte = row * 128 + ac4 * 8;
            *(s16x4*)(bT + (byte ^ ((row & 7) << 4))) = h;
        }
    };
    auto mfma_block = [&]() {
        const int am0 = w * 16;
#pragma unroll
        for (int ks = 0; ks < 2; ks++) {
            int k0 = ks * 32 + (lane >> 4) * 8;
            int ar = am0 + (lane & 15);
            bf16x8 af = *(bf16x8*)(aT + ((ar * 128 + k0 * 2) ^ ((ar & 7) << 4)));
#pragma unroll
            for (int nf = 0; nf < 16; nf++) {
                int nr = nf * 16 + (lane & 15);
                bf16x8 bfr = *(bf16x8*)(bT + ((nr * 128 + k0 * 2) ^ ((nr & 7) << 4)));
                acc[nf] = __builtin_amdgcn_mfma_f32_16x16x32_bf16(af, bfr, acc[nf], 0, 0, 0);
            }
        }
    };

    const int nIter = kchunk / 64;
    loadT(kbase, avA, bvA);
    for (int it = 0; it < nIter; it += 2) {
        stash(avA, bvA);
        __syncthreads();
        if (it + 1 < nIter) loadT(kbase + (it + 1) * 64, avB, bvB);
        mfma_block();
        __syncthreads();
        if (it + 1 < nIter) {
            stash(avB, bvB);
            __syncthreads();
            if (it + 2 < nIter) loadT(kbase + (it + 2) * 64, avA, bvA);
            mfma_block();
            __syncthreads();
        }
    }

#pragma unroll
    for (int nf = 0; nf < 16; nf++) {
        int col = nf * 16 + (lane & 15);
#pragma unroll
        for (int r = 0; r < 4; r++) {
            int row = m0 + w * 16 + (lane >> 4) * 4 + r;
            if (PART) {
                C[((size_t)y * B_SZ + row) * 256 + col] = acc[nf][r];
            } else {
                C[(size_t)row * 256 + col] = lrelu(acc[nf][r] + postBias[col]);
            }
        }
    }
}

// ---------------------------------------------------------------------------
// h1r = lrelu(sum_y part[y] + b1)
// ---------------------------------------------------------------------------
__global__ __launch_bounds__(256) void reduce8(
    const float* __restrict__ part, const float* __restrict__ b1,
    float* __restrict__ h1r)
{
    int g = blockIdx.x * 256 + threadIdx.x;     // float4 index
    size_t o = (size_t)g * 4;
    float4 s = *(const float4*)(part + o);
#pragma unroll
    for (int y = 1; y < 8; y++) {
        float4 v = *(const float4*)(part + (size_t)y * B_SZ * 256 + o);
        s.x += v.x; s.y += v.y; s.z += v.z; s.w += v.w;
    }
    float4 bb = *(const float4*)(b1 + ((g * 4) & 255));
    s.x = lrelu(s.x + bb.x); s.y = lrelu(s.y + bb.y);
    s.z = lrelu(s.z + bb.z); s.w = lrelu(s.w + bb.w);
    *(float4*)(h1r + o) = s;
}

// ---------------------------------------------------------------------------
// Fused U = Rz*Ry*Rx per (layer, qubit) — batch independent.
// ---------------------------------------------------------------------------
__global__ void qprep(const float* __restrict__ qp, float* __restrict__ U)
{
    int g = threadIdx.x;
    if (g >= 16) return;
    float ax = qp[g * 3 + 0], ay = qp[g * 3 + 1], az = qp[g * 3 + 2];
    float sa, ca, sb, cb, sg, cg;
    sincosf(ax * 0.5f, &sa, &ca);
    sincosf(ay * 0.5f, &sb, &cb);
    sincosf(az * 0.5f, &sg, &cg);
    float2 M00 = make_float2(cb * ca,  sb * sa);
    float2 M01 = make_float2(-sb * ca, -cb * sa);
    float2 M10 = make_float2(sb * ca,  -cb * sa);
    float2 M11 = make_float2(cb * ca,  -sb * sa);
    float2 e0 = make_float2(cg, -sg);
    float2 e1 = make_float2(cg,  sg);
    float2* out = (float2*)(U + g * 8);
    out[0] = cmul(e0, M00);
    out[1] = cmul(e0, M01);
    out[2] = cmul(e1, M10);
    out[3] = cmul(e1, M11);
}

// ---------------------------------------------------------------------------
// Fused qin + 8-qubit sim + measure. One wave per batch row, 4 amps/lane,
// all exchange via __shfl_xor — no barriers in the gate loop.
// Amp index a = 4*lane + j ; qubit q <-> amp bit (7-q).
// ---------------------------------------------------------------------------
__global__ __launch_bounds__(256) void qsim2(
    const float* __restrict__ h2, const float* __restrict__ W3,
    const float* __restrict__ b3, const float* __restrict__ Ug,
    float* __restrict__ qf)
{
    __shared__ float w3s[8 * 256];
    __shared__ float us[16 * 8];
    __shared__ float b3s[8];
    const int t = threadIdx.x, lane = t & 63, w = t >> 6;

    for (int i = t; i < 2048; i += 256) w3s[i] = W3[i];
    if (t < 128) us[t] = Ug[t];
    if (t < 8) b3s[t] = b3[t];
    __syncthreads();

    const int b = blockIdx.x * 4 + w;
    float4 hv = *(const float4*)(h2 + (size_t)b * 256 + lane * 4);

    // 8 dot products (K=256) via per-lane partial + butterfly
    float ang[8];
#pragma unroll
    for (int q = 0; q < 8; q++) {
        float4 wv = *(const float4*)(w3s + q * 256 + lane * 4);
        float p = hv.x * wv.x + hv.y * wv.y + hv.z * wv.z + hv.w * wv.w;
#pragma unroll
        for (int m = 1; m < 64; m <<= 1) p += __shfl_xor(p, m, 64);
        ang[q] = (p + b3s[q] + 1.0f) * 0.78539816339744831f;  // half-angle
    }
    // lanes 0..7 compute sincos, broadcast
    float myang = ang[0];
#pragma unroll
    for (int q = 1; q < 8; q++) if (lane == q) myang = ang[q];
    float s_ = 0.f, c_ = 0.f;
    if (lane < 8) sincosf(myang, &s_, &c_);
    float cs[8], sn[8];
#pragma unroll
    for (int q = 0; q < 8; q++) { cs[q] = __shfl(c_, q, 64); sn[q] = __shfl(s_, q, 64); }

    // initial product state amplitudes: mag * (-i)^popcount
    float mL = 1.f;
#pragma unroll
    for (int q = 0; q <= 5; q++) mL *= ((lane >> (5 - q)) & 1) ? sn[q] : cs[q];
    float mg0 = mL * cs[6] * cs[7], mg1 = mL * cs[6] * sn[7];
    float mg2 = mL * sn[6] * cs[7], mg3 = mL * sn[6] * sn[7];
    int pc = __popc(lane);
    auto ph = [](int k, float m) {
        k &= 3;
        if (k == 0) return make_float2(m, 0.f);
        if (k == 1) return make_float2(0.f, -m);
        if (k == 2) return make_float2(-m, 0.f);
        return make_float2(0.f, m);
    };
    float2 a0 = ph(pc, mg0), a1 = ph(pc + 1, mg1), a2 = ph(pc + 1, mg2), a3 = ph(pc + 2, mg3);

#pragma unroll
    for (int l = 0; l < 2; l++) {
#pragma unroll
        for (int q = 0; q < 8; q++) {
            const float* u = us + (l * 8 + q) * 8;
            float2 u00 = make_float2(u[0], u[1]), u01 = make_float2(u[2], u[3]);
            float2 u10 = make_float2(u[4], u[5]), u11 = make_float2(u[6], u[7]);
            if (q <= 5) {
                int sh = 5 - q, msk = 1 << sh, bit = (lane >> sh) & 1;
                float2 ud = bit ? u11 : u00, uo = bit ? u10 : u01;
                float2 p;
                p.x = __shfl_xor(a0.x, msk, 64); p.y = __shfl_xor(a0.y, msk, 64);
                a0 = cadd(cmul(ud, a0), cmul(uo, p));
                p.x = __shfl_xor(a1.x, msk, 64); p.y = __shfl_xor(a1.y, msk, 64);
                a1 = cadd(cmul(ud, a1), cmul(uo, p));
                p.x = __shfl_xor(a2.x, msk, 64); p.y = __shfl_xor(a2.y, msk, 64);
                a2 = cadd(cmul(ud, a2), cmul(uo, p));
                p.x = __shfl_xor(a3.x, msk, 64); p.y = __shfl_xor(a3.y, msk, 64);
                a3 = cadd(cmul(ud, a3), cmul(uo, p));
            } else if (q == 6) {
                float2 n0 = cadd(cmul(u00, a0), cmul(u01, a2));
                float2 n2 = cadd(cmul(u10, a0), cmul(u11, a2));
                float2 n1 = cadd(cmul(u00, a1), cmul(u01, a3));
                float2 n3 = cadd(cmul(u10, a1), cmul(u11, a3));
                a0 = n0; a1 = n1; a2 = n2; a3 = n3;
            } else {
                float2 n0 = cadd(cmul(u00, a0), cmul(u01, a1));
                float2 n1 = cadd(cmul(u10, a0), cmul(u11, a1));
                float2 n2 = cadd(cmul(u00, a2), cmul(u01, a3));
                float2 n3 = cadd(cmul(u10, a2), cmul(u11, a3));
                a0 = n0; a1 = n1; a2 = n2; a3 = n3;
            }
        }
        // CNOT chain c=0..6 (t=c+1)
#pragma unroll
        for (int c = 0; c <= 4; c++) {
            int tm = 1 << (4 - c);
            int cb = (lane >> (5 - c)) & 1;
            float2 p;
            p.x = __shfl_xor(a0.x, tm, 64); p.y = __shfl_xor(a0.y, tm, 64);
            if (cb) a0 = p;
            p.x = __shfl_xor(a1.x, tm, 64); p.y = __shfl_xor(a1.y, tm, 64);
            if (cb) a1 = p;
            p.x = __shfl_xor(a2.x, tm, 64); p.y = __shfl_xor(a2.y, tm, 64);
            if (cb) a2 = p;
            p.x = __shfl_xor(a3.x, tm, 64); p.y = __shfl_xor(a3.y, tm, 64);
            if (cb) a3 = p;
        }
        if (lane & 1) { float2 tmp = a0; a0 = a2; a2 = tmp; tmp = a1; a1 = a3; a3 = tmp; }
        { float2 tmp = a2; a2 = a3; a3 = tmp; }
    }

    // measurement
    float p0 = a0.x * a0.x + a0.y * a0.y, p1 = a1.x * a1.x + a1.y * a1.y;
    float p2 = a2.x * a2.x + a2.y * a2.y, p3 = a3.x * a3.x + a3.y * a3.y;
    float S = p0 + p1 + p2 + p3;
    float v0 = ((lane >> 5) & 1) ? -S : S;
    float v1 = ((lane >> 4) & 1) ? -S : S;
    float v2 = ((lane >> 3) & 1) ? -S : S;
    float v3 = ((lane >> 2) & 1) ? -S : S;
    float v4 = ((lane >> 1) & 1) ? -S : S;
    float v5 = (lane & 1) ? -S : S;
    float v6 = p0 + p1 - p2 - p3;
    float v7 = p0 - p1 + p2 - p3;
#pragma unroll
    for (int m = 1; m < 64; m <<= 1) {
        v0 += __shfl_xor(v0, m, 64); v1 += __shfl_xor(v1, m, 64);
        v2 += __shfl_xor(v2, m, 64); v3 += __shfl_xor(v3, m, 64);
        v4 += __shfl_xor(v4, m, 64); v5 += __shfl_xor(v5, m, 64);
        v6 += __shfl_xor(v6, m, 64); v7 += __shfl_xor(v7, m, 64);
    }
    if (lane == 0) {
        float* o = qf + (size_t)b * 8;
        o[0] = v0; o[1] = v1; o[2] = v2; o[3] = v3;
        o[4] = v4; o[5] = v5; o[6] = v6; o[7] = v7;
    }
}

// ---------------------------------------------------------------------------
// Head: comb[16] -> 256 -> 128 -> 1, MFMA with hi/lo bf16 compensation.
// BM=64, 256 threads (4 waves x 16 rows), grid 64.
// ---------------------------------------------------------------------------
__global__ __launch_bounds__(256) void head_mfma(
    const float* __restrict__ qf, const int* __restrict__ cid,
    const float* __restrict__ emb,
    const float* __restrict__ W4, const float* __restrict__ b4,
    const float* __restrict__ W5, const float* __restrict__ b5,
    const float* __restrict__ W6, const float* __restrict__ b6,
    float* __restrict__ out)
{
    __shared__ float comb[64 * 16];     // 4 KB
    __shared__ float w4s[256 * 16];     // 16 KB
    __shared__ float h3s[64 * 256];     // 64 KB, swizzled rows (1KB stride)
    const int t = threadIdx.x, lane = t & 63, w = t >> 6;
    const int m0 = blockIdx.x * 64;

    // stage W4 (256 rows x 14 -> 16)
    {
        const float* wr = W4 + t * 14;
        float* d = w4s + t * 16;
#pragma unroll
        for (int j = 0; j < 14; j++) d[j] = wr[j];
        d[14] = 0.f; d[15] = 0.f;
    }
    // stage comb (64 rows x 16)
    if (t < 128) {
        int r = t >> 1, half = t & 1;
        if (half == 0) {
            float4 q0 = *(const float4*)(qf + (size_t)(m0 + r) * 8);
            float4 q1 = *(const float4*)(qf + (size_t)(m0 + r) * 8 + 4);
            float* d = comb + r * 16;
            d[0] = q0.x; d[1] = q0.y; d[2] = q0.z; d[3] = q0.w;
            d[4] = q1.x; d[5] = q1.y; d[6] = q1.z; d[7] = q1.w;
        } else {
            const float* e = emb + cid[m0 + r] * 6;
            float* d = comb + r * 16 + 8;
#pragma unroll
            for (int j = 0; j < 6; j++) d[j] = e[j];
            d[6] = 0.f; d[7] = 0.f;
        }
    }
    __syncthreads();

    // ---- GEMM A: h3[64x256] = comb @ W4^T, K=16 (lanes>=32 contribute 0) ----
    f32x4 acc1[16];
#pragma unroll
    for (int i = 0; i < 16; i++) acc1[i] = (f32x4){0.f, 0.f, 0.f, 0.f};
    const bf16x8 Z = (bf16x8){0, 0, 0, 0, 0, 0, 0, 0};
    bf16x8 Ahi = Z, Alo = Z;
    const int k0 = (lane >> 4) * 8;
    const bool hasK = (lane < 32);
    if (hasK) {
        const float* p = comb + (w * 16 + (lane & 15)) * 16 + k0;
        mk_hilo(*(const float4*)p, *(const float4*)(p + 4), Ahi, Alo);
    }
#pragma unroll
    for (int nf = 0; nf < 16; nf++) {
        bf16x8 Bhi = Z, Blo = Z;
        if (hasK) {
            const float* p = w4s + (nf * 16 + (lane & 15)) * 16 + k0;
            mk_hilo(*(const float4*)p, *(const float4*)(p + 4), Bhi, Blo);
        }
        acc1[nf] = __builtin_amdgcn_mfma_f32_16x16x32_bf16(Ahi, Bhi, acc1[nf], 0, 0, 0);
        acc1[nf] = __builtin_amdgcn_mfma_f32_16x16x32_bf16(Ahi, Blo, acc1[nf], 0, 0, 0);
        acc1[nf] = __builtin_amdgcn_mfma_f32_16x16x32_bf16(Alo, Bhi, acc1[nf], 0, 0, 0);
    }
    // h3 = lrelu(acc1 + b4) -> LDS f32, swizzled
#pragma unroll
    for (int nf = 0; nf < 16; nf++) {
        int col = nf * 16 + (lane & 15);
        float bc = b4[col];
#pragma unroll
        for (int r = 0; r < 4; r++) {
            int row = w * 16 + (lane >> 4) * 4 + r;
            float v = lrelu(acc1[nf][r] + bc);
            int byte = row * 1024 + col * 4;
            *(float*)((char*)h3s + (byte ^ ((row & 7) << 4))) = v;
        }
    }
    __syncthreads();

    // ---- GEMM B: h4[64x128] = h3 @ W5^T, K=256, hi/lo both sides ----
    f32x4 acc2[8];
#pragma unroll
    for (int i = 0; i < 8; i++) acc2[i] = (f32x4){0.f, 0.f, 0.f, 0.f};
#pragma unroll
    for (int ks = 0; ks < 8; ks++) {
        int kf = ks * 32 + (lane >> 4) * 8;
        int row = w * 16 + (lane & 15);
        int base = row * 1024 + kf * 4;
        float4 x0 = *(float4*)((char*)h3s + (base ^ ((row & 7) << 4)));
        float4 x1 = *(float4*)((char*)h3s + ((base + 16) ^ ((row & 7) << 4)));
        bf16x8 Ah, Al;
        mk_hilo(x0, x1, Ah, Al);
#pragma unroll
        for (int nf = 0; nf < 8; nf++) {
            int n = nf * 16 + (lane & 15);
            const float* wp = W5 + (size_t)n * 256 + kf;
            float4 w0 = *(const float4*)wp;
            float4 w1 = *(const float4*)(wp + 4);
            bf16x8 Bh, Bl;
            mk_hilo(w0, w1, Bh, Bl);
            acc2[nf] = __builtin_amdgcn_mfma_f32_16x16x32_bf16(Ah, Bh, acc2[nf], 0, 0, 0);
            acc2[nf] = __builtin_amdgcn_mfma_f32_16x16x32_bf16(Ah, Bl, acc2[nf], 0, 0, 0);
            acc2[nf] = __builtin_amdgcn_mfma_f32_16x16x32_bf16(Al, Bh, acc2[nf], 0, 0, 0);
        }
    }

    // ---- epilogue: out[row] = sum_col lrelu(acc2+b5) * W6[col] + b6 ----
    float vs0 = 0.f, vs1 = 0.f, vs2 = 0.f, vs3 = 0.f;
#pragma unroll
    for (int nf = 0; nf < 8; nf++) {
        int col = nf * 16 + (lane & 15);
        float b5c = b5[col], w6c = W6[col];
        float h40 = lrelu(acc2[nf][0] + b5c);
        float h41 = lrelu(acc2[nf][1] + b5c);
        float h42 = lrelu(acc2[nf][2] + b5c);
        float h43 = lrelu(acc2[nf][3] + b5c);
        vs0 += h40 * w6c; vs1 += h41 * w6c; vs2 += h42 * w6c; vs3 += h43 * w6c;
    }
#pragma unroll
    for (int m = 1; m < 16; m <<= 1) {
        vs0 += __shfl_xor(vs0, m, 64); vs1 += __shfl_xor(vs1, m, 64);
        vs2 += __shfl_xor(vs2, m, 64); vs3 += __shfl_xor(vs3, m, 64);
    }
    if ((lane & 15) == 0) {
        float bb = b6[0];
        int row = m0 + w * 16 + (lane >> 4) * 4;
        out[row + 0] = vs0 + bb;
        out[row + 1] = vs1 + bb;
        out[row + 2] = vs2 + bb;
        out[row + 3] = vs3 + bb;
    }
}

extern "C" void kernel_launch(void* const* d_in, const int* in_sizes, int n_in,
                              void* d_out, int out_size, void* d_ws, size_t ws_size,
                              hipStream_t stream)
{
    const float* img = (const float*)d_in[0];
    const int*   cid = (const int*)d_in[1];
    const float* W1  = (const float*)d_in[2];
    const float* b1  = (const float*)d_in[3];
    const float* W2  = (const float*)d_in[4];
    const float* b2  = (const float*)d_in[5];
    const float* W3  = (const float*)d_in[6];
    const float* b3  = (const float*)d_in[7];
    const float* qp  = (const float*)d_in[8];
    const float* emb = (const float*)d_in[9];
    const float* W4  = (const float*)d_in[10];
    const float* b4  = (const float*)d_in[11];
    const float* W5  = (const float*)d_in[12];
    const float* b5  = (const float*)d_in[13];
    const float* W6  = (const float*)d_in[14];
    const float* b6  = (const float*)d_in[15];

    float* part   = (float*)d_ws;                          // 8 * 4096*256 f32
    float* h1r    = part + (size_t)8 * B_SZ * HDIM;        // 4096*256
    float* h2     = h1r + (size_t)B_SZ * HDIM;             // 4096*256
    float* qfbuf  = h2 + (size_t)B_SZ * HDIM;              // 4096*8
    float* Umat   = qfbuf + (size_t)B_SZ * NQ;             // 16*8

    // GEMM1: split-K=8, XCD-pinned chunks, partial stores
    gemm_bt<8, true><<<256, 512, 0, stream>>>(img, W1, nullptr, part, DDIM);
    // h1r = lrelu(sum partials + b1)
    reduce8<<<B_SZ * HDIM / 4 / 256, 256, 0, stream>>>(part, b1, h1r);
    // GEMM2: h2 = lrelu(h1r @ W2^T + b2)
    gemm_bt<1, false><<<32, 512, 0, stream>>>(h1r, W2, b2, h2, HDIM);

    qprep<<<1, 64, 0, stream>>>(qp, Umat);
    // fused qin + sim + measure
    qsim2<<<B_SZ / 4, 256, 0, stream>>>(h2, W3, b3, Umat, qfbuf);
    head_mfma<<<B_SZ / 64, 256, 0, stream>>>(qfbuf, cid, emb, W4, b4, W5, b5,
                                             W6, b6, (float*)d_out);
}

// Round 4
// 491.131 us; speedup vs baseline: 1.4778x; 1.0362x over previous
//
#include <hip/hip_runtime.h>
#include <hip/hip_bf16.h>

#define B_SZ 4096
#define DDIM 16384
#define HDIM 256
#define NQ 8

typedef __attribute__((ext_vector_type(8))) short bf16x8;
typedef __attribute__((ext_vector_type(4))) short s16x4;
typedef __attribute__((ext_vector_type(4))) float f32x4;
typedef unsigned int u32;

__device__ inline short f2bf(float f) {
    union { float f; unsigned u; } v; v.f = f;
    unsigned r = v.u + 0x7fffu + ((v.u >> 16) & 1u);
    return (short)(r >> 16);
}
__device__ inline float bf2f(short h) {
    union { unsigned u; float f; } v; v.u = ((unsigned)(unsigned short)h) << 16;
    return v.f;
}
__device__ inline float lrelu(float x) { return x >= 0.f ? x : 0.2f * x; }

__device__ inline float2 cmul(float2 a, float2 b) {
    return make_float2(a.x * b.x - a.y * b.y, a.x * b.y + a.y * b.x);
}
__device__ inline float2 cadd(float2 a, float2 b) {
    return make_float2(a.x + b.x, a.y + b.y);
}

// async global->LDS, 16B per lane. lds = wave-uniform base; g = per-lane src.
__device__ inline void async16(void* lds, const void* g) {
    __builtin_amdgcn_global_load_lds(
        (const __attribute__((address_space(1))) u32*)g,
        (__attribute__((address_space(3))) u32*)lds, 16, 0, 0);
}

// hi/lo bf16 split of 8 f32 (compensated bf16 "fp32-ish" path)
__device__ inline void mk_hilo(float4 a, float4 b, bf16x8& hi, bf16x8& lo) {
    float xs[8] = {a.x, a.y, a.z, a.w, b.x, b.y, b.z, b.w};
#pragma unroll
    for (int j = 0; j < 8; j++) {
        short h = f2bf(xs[j]);
        hi[j] = h;
        lo[j] = f2bf(xs[j] - bf2f(h));
    }
}

// ---------------------------------------------------------------------------
// convW: one-shot weight preprocessing (runs every call; ~5us).
//  blocks [0,4096):    W1 -> W1s  bf16 pre-swizzled k-block tiles (8 MB)
//  blocks [4096,4160): W2 -> W2s  same layout (128 KB)
//  blocks [4160,4192): W5 -> W5h/W5l bf16 hi/lo planes (row-major 128x256)
//  block  4192:        W4 -> W4h/W4l padded 256x32 + fused qprep -> Umat
// k-block tile layout: block kb holds rows 0..R-1, cols kb*64..kb*64+63 as
// bf16; byte offset within 32KB block = (r*128 + c4*8) ^ ((r&7)<<4).
// ---------------------------------------------------------------------------
__global__ __launch_bounds__(256) void convW(
    const float* __restrict__ W1, const float* __restrict__ W2,
    const float* __restrict__ W4, const float* __restrict__ W5,
    const float* __restrict__ qp,
    char* __restrict__ W1s, char* __restrict__ W2s,
    short* __restrict__ W4h, short* __restrict__ W4l,
    short* __restrict__ W5h, short* __restrict__ W5l,
    float* __restrict__ Umat)
{
    const int bid = blockIdx.x, t = threadIdx.x;
    if (bid < 4096) {
        int idx = bid * 256 + t;               // f4 index, W1 = 256 x 16384
        int r = idx >> 12, cg = idx & 4095;
        int kb = cg >> 4, c4 = cg & 15;
        float4 v = *(const float4*)(W1 + ((size_t)idx << 2));
        s16x4 h = (s16x4){f2bf(v.x), f2bf(v.y), f2bf(v.z), f2bf(v.w)};
        int byte = (r * 128 + c4 * 8) ^ ((r & 7) << 4);
        *(s16x4*)(W1s + kb * 32768 + byte) = h;
    } else if (bid < 4160) {
        int idx = (bid - 4096) * 256 + t;      // f4 index, W2 = 256 x 256
        int r = idx >> 6, cg = idx & 63;
        int kb = cg >> 4, c4 = cg & 15;
        float4 v = *(const float4*)(W2 + ((size_t)idx << 2));
        s16x4 h = (s16x4){f2bf(v.x), f2bf(v.y), f2bf(v.z), f2bf(v.w)};
        int byte = (r * 128 + c4 * 8) ^ ((r & 7) << 4);
        *(s16x4*)(W2s + kb * 32768 + byte) = h;
    } else if (bid < 4192) {
        int idx = (bid - 4160) * 256 + t;      // f4 index, W5 = 128 x 256
        float4 v = *(const float4*)(W5 + ((size_t)idx << 2));
        float xs[4] = {v.x, v.y, v.z, v.w};
        s16x4 hi, lo;
#pragma unroll
        for (int j = 0; j < 4; j++) {
            short h = f2bf(xs[j]);
            hi[j] = h;
            lo[j] = f2bf(xs[j] - bf2f(h));
        }
        *(s16x4*)(W5h + (size_t)idx * 4) = hi;
        *(s16x4*)(W5l + (size_t)idx * 4) = lo;
    } else {
        // W4: 256 rows x 14 -> padded 32
        const float* wr = W4 + t * 14;
        short* dh = W4h + t * 32;
        short* dl = W4l + t * 32;
#pragma unroll
        for (int j = 0; j < 14; j++) {
            float x = wr[j];
            short h = f2bf(x);
            dh[j] = h;
            dl[j] = f2bf(x - bf2f(h));
        }
#pragma unroll
        for (int j = 14; j < 32; j++) { dh[j] = 0; dl[j] = 0; }
        if (t < 16) {
            float ax = qp[t * 3 + 0], ay = qp[t * 3 + 1], az = qp[t * 3 + 2];
            float sa, ca, sb, cb, sg, cg;
            sincosf(ax * 0.5f, &sa, &ca);
            sincosf(ay * 0.5f, &sb, &cb);
            sincosf(az * 0.5f, &sg, &cg);
            float2 M00 = make_float2(cb * ca,  sb * sa);
            float2 M01 = make_float2(-sb * ca, -cb * sa);
            float2 M10 = make_float2(sb * ca,  -cb * sa);
            float2 M11 = make_float2(cb * ca,  -sb * sa);
            float2 e0 = make_float2(cg, -sg);
            float2 e1 = make_float2(cg,  sg);
            float2* out = (float2*)(Umat + t * 8);
            out[0] = cmul(e0, M00);
            out[1] = cmul(e0, M01);
            out[2] = cmul(e1, M10);
            out[3] = cmul(e1, M11);
        }
    }
}

// ---------------------------------------------------------------------------
// GEMM1: part[y][4096x256] = img[4096x16384] @ W1^T, split-K=8 (y = bid&7,
// XCD-pinned). A: reg-staged f32->bf16. B: global_load_lds from pre-swizzled
// W1s (linear dest + pre-swizzled source + swizzled read). Double-buffered
// LDS (96 KB), one barrier per K-iter, loads issued before MFMA phase.
// ---------------------------------------------------------------------------
__global__ __launch_bounds__(512, 2) void gemm1(
    const float* __restrict__ img, const char* __restrict__ W1s,
    float* __restrict__ part)
{
    __shared__ char smem[2][49152];   // per buf: A 16KB @0, B 32KB @16384

    const int bid = blockIdx.x;
    const int y = bid & 7, x = bid >> 3;
    const int m0 = x * 128;
    const int t = threadIdx.x, lane = t & 63, w = t >> 6;
    const int arow = t >> 4, ac4 = t & 15;

    f32x4 acc[16];
#pragma unroll
    for (int i = 0; i < 16; i++) acc[i] = (f32x4){0.f, 0.f, 0.f, 0.f};
    float4 ra[4];

    const float* aBase = img + (size_t)m0 * DDIM + y * 2048;
    const char*  bBase = W1s + (size_t)(y * 32) * 32768;

    auto loadA = [&](int it) {
#pragma unroll
        for (int i = 0; i < 4; i++)
            ra[i] = *(const float4*)(aBase + (size_t)(arow + 32 * i) * DDIM + it * 64 + ac4 * 4);
    };
    auto issueB = [&](int it, int buf) {
        const char* src = bBase + it * 32768 + w * 4096 + lane * 16;
        char* dst = &smem[buf][16384 + w * 4096];
#pragma unroll
        for (int i = 0; i < 4; i++)
            async16(dst + i * 1024, src + i * 1024);
    };
    auto writeA = [&](int buf) {
#pragma unroll
        for (int i = 0; i < 4; i++) {
            int row = arow + 32 * i;
            float4 v = ra[i];
            s16x4 h = (s16x4){f2bf(v.x), f2bf(v.y), f2bf(v.z), f2bf(v.w)};
            int byte = (row * 128 + ac4 * 8) ^ ((row & 7) << 4);
            *(s16x4*)(&smem[buf][byte]) = h;
        }
    };
    auto mfma_block = [&](int buf) {
        const char* aT = &smem[buf][0];
        const char* bT = &smem[buf][16384];
#pragma unroll
        for (int ks = 0; ks < 2; ks++) {
            int k0 = ks * 32 + (lane >> 4) * 8;
            int ar = w * 16 + (lane & 15);
            bf16x8 af = *(const bf16x8*)(aT + ((ar * 128 + k0 * 2) ^ ((ar & 7) << 4)));
#pragma unroll
            for (int nf = 0; nf < 16; nf++) {
                int nr = nf * 16 + (lane & 15);
                bf16x8 bfr = *(const bf16x8*)(bT + ((nr * 128 + k0 * 2) ^ ((nr & 7) << 4)));
                acc[nf] = __builtin_amdgcn_mfma_f32_16x16x32_bf16(af, bfr, acc[nf], 0, 0, 0);
            }
        }
    };

    loadA(0);
    issueB(0, 0);
    writeA(0);
    __syncthreads();
    for (int it = 0; it < 32; ++it) {
        int bc = it & 1, bn = bc ^ 1;
        if (it < 31) { loadA(it + 1); issueB(it + 1, bn); }
        mfma_block(bc);
        if (it < 31) writeA(bn);
        __syncthreads();
    }

#pragma unroll
    for (int nf = 0; nf < 16; nf++) {
        int col = nf * 16 + (lane & 15);
#pragma unroll
        for (int r = 0; r < 4; r++) {
            int row = m0 + w * 16 + (lane >> 4) * 4 + r;
            part[((size_t)y * B_SZ + row) * 256 + col] = acc[nf][r];
        }
    }
}

// ---------------------------------------------------------------------------
// GEMM2: h2 = lrelu( lrelu(sum_y part + b1) @ W2^T + b2 ).  Fuses the split-K
// reduction + bias + leaky into A-staging. BM=64 (grid 64), BN=256, K=256.
// 8 waves: (w&3) = row group, (w>>2) = N-half.
// ---------------------------------------------------------------------------
__global__ __launch_bounds__(512) void gemm2(
    const float* __restrict__ part, const char* __restrict__ W2s,
    const float* __restrict__ b1, const float* __restrict__ b2,
    float* __restrict__ h2)
{
    __shared__ char smem[8192 + 32768];   // A 64x64 bf16 swz, B 256x64 bf16 swz
    char* aT = smem;
    char* bT = smem + 8192;

    const int m0 = blockIdx.x * 64;
    const int t = threadIdx.x, lane = t & 63, w = t >> 6;
    const int wq = w & 3, half = w >> 2;

    f32x4 acc[8];
#pragma unroll
    for (int i = 0; i < 8; i++) acc[i] = (f32x4){0.f, 0.f, 0.f, 0.f};

    for (int it = 0; it < 4; ++it) {
        // B: async from pre-swizzled W2s
        {
            const char* src = W2s + it * 32768 + w * 4096 + lane * 16;
            char* dst = bT + w * 4096;
#pragma unroll
            for (int i = 0; i < 4; i++)
                async16(dst + i * 1024, src + i * 1024);
        }
        // A: 8-way partial sum + b1 + lrelu -> bf16 swizzled
#pragma unroll
        for (int j = 0; j < 2; j++) {
            int g = t + j * 512;
            int row = g >> 4, c4 = g & 15;
            int kg = it * 64 + c4 * 4;
            float4 s = make_float4(0.f, 0.f, 0.f, 0.f);
#pragma unroll
            for (int yy = 0; yy < 8; yy++) {
                float4 v = *(const float4*)(part + ((size_t)yy * B_SZ + m0 + row) * 256 + kg);
                s.x += v.x; s.y += v.y; s.z += v.z; s.w += v.w;
            }
            float4 bb = *(const float4*)(b1 + kg);
            s.x = lrelu(s.x + bb.x); s.y = lrelu(s.y + bb.y);
            s.z = lrelu(s.z + bb.z); s.w = lrelu(s.w + bb.w);
            s16x4 h = (s16x4){f2bf(s.x), f2bf(s.y), f2bf(s.z), f2bf(s.w)};
            int byte = (row * 128 + c4 * 8) ^ ((row & 7) << 4);
            *(s16x4*)(aT + byte) = h;
        }
        __syncthreads();
#pragma unroll
        for (int ks = 0; ks < 2; ks++) {
            int k0 = ks * 32 + (lane >> 4) * 8;
            int ar = wq * 16 + (lane & 15);
            bf16x8 af = *(const bf16x8*)(aT + ((ar * 128 + k0 * 2) ^ ((ar & 7) << 4)));
#pragma unroll
            for (int nf = 0; nf < 8; nf++) {
                int nr = half * 128 + nf * 16 + (lane & 15);
                bf16x8 bfr = *(const bf16x8*)(bT + ((nr * 128 + k0 * 2) ^ ((nr & 7) << 4)));
                acc[nf] = __builtin_amdgcn_mfma_f32_16x16x32_bf16(af, bfr, acc[nf], 0, 0, 0);
            }
        }
        __syncthreads();
    }

#pragma unroll
    for (int nf = 0; nf < 8; nf++) {
        int col = half * 128 + nf * 16 + (lane & 15);
        float bb = b2[col];
#pragma unroll
        for (int r = 0; r < 4; r++) {
            int row = m0 + wq * 16 + (lane >> 4) * 4 + r;
            h2[(size_t)row * 256 + col] = lrelu(acc[nf][r] + bb);
        }
    }
}

// ---------------------------------------------------------------------------
// Fused qin + 8-qubit sim + measure. One wave per batch row, 4 amps/lane,
// all exchange via __shfl_xor — no barriers in the gate loop.
// ---------------------------------------------------------------------------
__global__ __launch_bounds__(256) void qsim2(
    const float* __restrict__ h2, const float* __restrict__ W3,
    const float* __restrict__ b3, const float* __restrict__ Ug,
    float* __restrict__ qf)
{
    __shared__ float w3s[8 * 256];
    __shared__ float us[16 * 8];
    __shared__ float b3s[8];
    const int t = threadIdx.x, lane = t & 63, w = t >> 6;

    for (int i = t; i < 2048; i += 256) w3s[i] = W3[i];
    if (t < 128) us[t] = Ug[t];
    if (t < 8) b3s[t] = b3[t];
    __syncthreads();

    const int b = blockIdx.x * 4 + w;
    float4 hv = *(const float4*)(h2 + (size_t)b * 256 + lane * 4);

    float ang[8];
#pragma unroll
    for (int q = 0; q < 8; q++) {
        float4 wv = *(const float4*)(w3s + q * 256 + lane * 4);
        float p = hv.x * wv.x + hv.y * wv.y + hv.z * wv.z + hv.w * wv.w;
#pragma unroll
        for (int m = 1; m < 64; m <<= 1) p += __shfl_xor(p, m, 64);
        ang[q] = (p + b3s[q] + 1.0f) * 0.78539816339744831f;  // half-angle
    }
    float myang = ang[0];
#pragma unroll
    for (int q = 1; q < 8; q++) if (lane == q) myang = ang[q];
    float s_ = 0.f, c_ = 0.f;
    if (lane < 8) sincosf(myang, &s_, &c_);
    float cs[8], sn[8];
#pragma unroll
    for (int q = 0; q < 8; q++) { cs[q] = __shfl(c_, q, 64); sn[q] = __shfl(s_, q, 64); }

    float mL = 1.f;
#pragma unroll
    for (int q = 0; q <= 5; q++) mL *= ((lane >> (5 - q)) & 1) ? sn[q] : cs[q];
    float mg0 = mL * cs[6] * cs[7], mg1 = mL * cs[6] * sn[7];
    float mg2 = mL * sn[6] * cs[7], mg3 = mL * sn[6] * sn[7];
    int pc = __popc(lane);
    auto ph = [](int k, float m) {
        k &= 3;
        if (k == 0) return make_float2(m, 0.f);
        if (k == 1) return make_float2(0.f, -m);
        if (k == 2) return make_float2(-m, 0.f);
        return make_float2(0.f, m);
    };
    float2 a0 = ph(pc, mg0), a1 = ph(pc + 1, mg1), a2 = ph(pc + 1, mg2), a3 = ph(pc + 2, mg3);

#pragma unroll
    for (int l = 0; l < 2; l++) {
#pragma unroll
        for (int q = 0; q < 8; q++) {
            const float* u = us + (l * 8 + q) * 8;
            float2 u00 = make_float2(u[0], u[1]), u01 = make_float2(u[2], u[3]);
            float2 u10 = make_float2(u[4], u[5]), u11 = make_float2(u[6], u[7]);
            if (q <= 5) {
                int sh = 5 - q, msk = 1 << sh, bit = (lane >> sh) & 1;
                float2 ud = bit ? u11 : u00, uo = bit ? u10 : u01;
                float2 p;
                p.x = __shfl_xor(a0.x, msk, 64); p.y = __shfl_xor(a0.y, msk, 64);
                a0 = cadd(cmul(ud, a0), cmul(uo, p));
                p.x = __shfl_xor(a1.x, msk, 64); p.y = __shfl_xor(a1.y, msk, 64);
                a1 = cadd(cmul(ud, a1), cmul(uo, p));
                p.x = __shfl_xor(a2.x, msk, 64); p.y = __shfl_xor(a2.y, msk, 64);
                a2 = cadd(cmul(ud, a2), cmul(uo, p));
                p.x = __shfl_xor(a3.x, msk, 64); p.y = __shfl_xor(a3.y, msk, 64);
                a3 = cadd(cmul(ud, a3), cmul(uo, p));
            } else if (q == 6) {
                float2 n0 = cadd(cmul(u00, a0), cmul(u01, a2));
                float2 n2 = cadd(cmul(u10, a0), cmul(u11, a2));
                float2 n1 = cadd(cmul(u00, a1), cmul(u01, a3));
                float2 n3 = cadd(cmul(u10, a1), cmul(u11, a3));
                a0 = n0; a1 = n1; a2 = n2; a3 = n3;
            } else {
                float2 n0 = cadd(cmul(u00, a0), cmul(u01, a1));
                float2 n1 = cadd(cmul(u10, a0), cmul(u11, a1));
                float2 n2 = cadd(cmul(u00, a2), cmul(u01, a3));
                float2 n3 = cadd(cmul(u10, a2), cmul(u11, a3));
                a0 = n0; a1 = n1; a2 = n2; a3 = n3;
            }
        }
#pragma unroll
        for (int c = 0; c <= 4; c++) {
            int tm = 1 << (4 - c);
            int cb = (lane >> (5 - c)) & 1;
            float2 p;
            p.x = __shfl_xor(a0.x, tm, 64); p.y = __shfl_xor(a0.y, tm, 64);
            if (cb) a0 = p;
            p.x = __shfl_xor(a1.x, tm, 64); p.y = __shfl_xor(a1.y, tm, 64);
            if (cb) a1 = p;
            p.x = __shfl_xor(a2.x, tm, 64); p.y = __shfl_xor(a2.y, tm, 64);
            if (cb) a2 = p;
            p.x = __shfl_xor(a3.x, tm, 64); p.y = __shfl_xor(a3.y, tm, 64);
            if (cb) a3 = p;
        }
        if (lane & 1) { float2 tmp = a0; a0 = a2; a2 = tmp; tmp = a1; a1 = a3; a3 = tmp; }
        { float2 tmp = a2; a2 = a3; a3 = tmp; }
    }

    float p0 = a0.x * a0.x + a0.y * a0.y, p1 = a1.x * a1.x + a1.y * a1.y;
    float p2 = a2.x * a2.x + a2.y * a2.y, p3 = a3.x * a3.x + a3.y * a3.y;
    float S = p0 + p1 + p2 + p3;
    float v0 = ((lane >> 5) & 1) ? -S : S;
    float v1 = ((lane >> 4) & 1) ? -S : S;
    float v2 = ((lane >> 3) & 1) ? -S : S;
    float v3 = ((lane >> 2) & 1) ? -S : S;
    float v4 = ((lane >> 1) & 1) ? -S : S;
    float v5 = (lane & 1) ? -S : S;
    float v6 = p0 + p1 - p2 - p3;
    float v7 = p0 - p1 + p2 - p3;
#pragma unroll
    for (int m = 1; m < 64; m <<= 1) {
        v0 += __shfl_xor(v0, m, 64); v1 += __shfl_xor(v1, m, 64);
        v2 += __shfl_xor(v2, m, 64); v3 += __shfl_xor(v3, m, 64);
        v4 += __shfl_xor(v4, m, 64); v5 += __shfl_xor(v5, m, 64);
        v6 += __shfl_xor(v6, m, 64); v7 += __shfl_xor(v7, m, 64);
    }
    if (lane == 0) {
        float* o = qf + (size_t)b * 8;
        o[0] = v0; o[1] = v1; o[2] = v2; o[3] = v3;
        o[4] = v4; o[5] = v5; o[6] = v6; o[7] = v7;
    }
}

// ---------------------------------------------------------------------------
// Head: comb[pad 32] -> 256 -> 128 -> 1. BM=64, 4 waves, grid 64.
// Weights pre-converted to bf16 hi/lo planes (W4h/l: 256x32, W5h/l: 128x256).
// ---------------------------------------------------------------------------
__global__ __launch_bounds__(256) void head_mfma(
    const float* __restrict__ qf, const int* __restrict__ cid,
    const float* __restrict__ emb,
    const short* __restrict__ W4h, const short* __restrict__ W4l,
    const float* __restrict__ b4,
    const short* __restrict__ W5h, const short* __restrict__ W5l,
    const float* __restrict__ b5,
    const float* __restrict__ W6, const float* __restrict__ b6,
    float* __restrict__ out)
{
    __shared__ float comb[64 * 32];     // 8 KB (cols 14..31 zero)
    __shared__ float h3s[64 * 256];     // 64 KB, swizzled
    const int t = threadIdx.x, lane = t & 63, w = t >> 6;
    const int m0 = blockIdx.x * 64;

    if (t < 128) {
        int r = t >> 1, half = t & 1;
        float* d = comb + r * 32;
        if (half == 0) {
            float4 q0 = *(const float4*)(qf + (size_t)(m0 + r) * 8);
            float4 q1 = *(const float4*)(qf + (size_t)(m0 + r) * 8 + 4);
            d[0] = q0.x; d[1] = q0.y; d[2] = q0.z; d[3] = q0.w;
            d[4] = q1.x; d[5] = q1.y; d[6] = q1.z; d[7] = q1.w;
#pragma unroll
            for (int j = 16; j < 24; j++) d[j] = 0.f;
        } else {
            const float* e = emb + cid[m0 + r] * 6;
#pragma unroll
            for (int j = 0; j < 6; j++) d[8 + j] = e[j];
            d[14] = 0.f; d[15] = 0.f;
#pragma unroll
            for (int j = 24; j < 32; j++) d[j] = 0.f;
        }
    }
    __syncthreads();

    // ---- GEMM A: h3[64x256] = comb @ W4^T, K=32 (padded) ----
    f32x4 acc1[16];
#pragma unroll
    for (int i = 0; i < 16; i++) acc1[i] = (f32x4){0.f, 0.f, 0.f, 0.f};
    const int k0 = (lane >> 4) * 8;
    bf16x8 Ahi, Alo;
    {
        const float* p = comb + (w * 16 + (lane & 15)) * 32 + k0;
        mk_hilo(*(const float4*)p, *(const float4*)(p + 4), Ahi, Alo);
    }
#pragma unroll
    for (int nf = 0; nf < 16; nf++) {
        int n = nf * 16 + (lane & 15);
        bf16x8 Bhi = *(const bf16x8*)(W4h + n * 32 + k0);
        bf16x8 Blo = *(const bf16x8*)(W4l + n * 32 + k0);
        acc1[nf] = __builtin_amdgcn_mfma_f32_16x16x32_bf16(Ahi, Bhi, acc1[nf], 0, 0, 0);
        acc1[nf] = __builtin_amdgcn_mfma_f32_16x16x32_bf16(Ahi, Blo, acc1[nf], 0, 0, 0);
        acc1[nf] = __builtin_amdgcn_mfma_f32_16x16x32_bf16(Alo, Bhi, acc1[nf], 0, 0, 0);
    }
#pragma unroll
    for (int nf = 0; nf < 16; nf++) {
        int col = nf * 16 + (lane & 15);
        float bc = b4[col];
#pragma unroll
        for (int r = 0; r < 4; r++) {
            int row = w * 16 + (lane >> 4) * 4 + r;
            float v = lrelu(acc1[nf][r] + bc);
            int byte = row * 1024 + col * 4;
            *(float*)((char*)h3s + (byte ^ ((row & 7) << 4))) = v;
        }
    }
    __syncthreads();

    // ---- GEMM B: h4[64x128] = h3 @ W5^T, K=256 ----
    f32x4 acc2[8];
#pragma unroll
    for (int i = 0; i < 8; i++) acc2[i] = (f32x4){0.f, 0.f, 0.f, 0.f};
#pragma unroll
    for (int ks = 0; ks < 8; ks++) {
        int kf = ks * 32 + (lane >> 4) * 8;
        int row = w * 16 + (lane & 15);
        int base = row * 1024 + kf * 4;
        float4 x0 = *(float4*)((char*)h3s + (base ^ ((row & 7) << 4)));
        float4 x1 = *(float4*)((char*)h3s + ((base + 16) ^ ((row & 7) << 4)));
        bf16x8 Ah, Al;
        mk_hilo(x0, x1, Ah, Al);
#pragma unroll
        for (int nf = 0; nf < 8; nf++) {
            int n = nf * 16 + (lane & 15);
            bf16x8 Bh = *(const bf16x8*)(W5h + n * 256 + kf);
            bf16x8 Bl = *(const bf16x8*)(W5l + n * 256 + kf);
            acc2[nf] = __builtin_amdgcn_mfma_f32_16x16x32_bf16(Ah, Bh, acc2[nf], 0, 0, 0);
            acc2[nf] = __builtin_amdgcn_mfma_f32_16x16x32_bf16(Ah, Bl, acc2[nf], 0, 0, 0);
            acc2[nf] = __builtin_amdgcn_mfma_f32_16x16x32_bf16(Al, Bh, acc2[nf], 0, 0, 0);
        }
    }

    float vs0 = 0.f, vs1 = 0.f, vs2 = 0.f, vs3 = 0.f;
#pragma unroll
    for (int nf = 0; nf < 8; nf++) {
        int col = nf * 16 + (lane & 15);
        float b5c = b5[col], w6c = W6[col];
        vs0 += lrelu(acc2[nf][0] + b5c) * w6c;
        vs1 += lrelu(acc2[nf][1] + b5c) * w6c;
        vs2 += lrelu(acc2[nf][2] + b5c) * w6c;
        vs3 += lrelu(acc2[nf][3] + b5c) * w6c;
    }
#pragma unroll
    for (int m = 1; m < 16; m <<= 1) {
        vs0 += __shfl_xor(vs0, m, 64); vs1 += __shfl_xor(vs1, m, 64);
        vs2 += __shfl_xor(vs2, m, 64); vs3 += __shfl_xor(vs3, m, 64);
    }
    if ((lane & 15) == 0) {
        float bb = b6[0];
        int row = m0 + w * 16 + (lane >> 4) * 4;
        out[row + 0] = vs0 + bb;
        out[row + 1] = vs1 + bb;
        out[row + 2] = vs2 + bb;
        out[row + 3] = vs3 + bb;
    }
}

extern "C" void kernel_launch(void* const* d_in, const int* in_sizes, int n_in,
                              void* d_out, int out_size, void* d_ws, size_t ws_size,
                              hipStream_t stream)
{
    const float* img = (const float*)d_in[0];
    const int*   cid = (const int*)d_in[1];
    const float* W1  = (const float*)d_in[2];
    const float* b1  = (const float*)d_in[3];
    const float* W2  = (const float*)d_in[4];
    const float* b2  = (const float*)d_in[5];
    const float* W3  = (const float*)d_in[6];
    const float* b3  = (const float*)d_in[7];
    const float* qp  = (const float*)d_in[8];
    const float* emb = (const float*)d_in[9];
    const float* W4  = (const float*)d_in[10];
    const float* b4  = (const float*)d_in[11];
    const float* W5  = (const float*)d_in[12];
    const float* b5  = (const float*)d_in[13];
    const float* W6  = (const float*)d_in[14];
    const float* b6  = (const float*)d_in[15];

    // workspace layout (all 64-byte aligned)
    char* ws = (char*)d_ws;
    float* part  = (float*)(ws + 0);              // 8*4096*256 f32 = 33554432 B
    float* h2    = (float*)(ws + 33554432);       // 4096*256 f32   =  4194304 B
    float* qfbuf = (float*)(ws + 37748736);       // 4096*8 f32     =   131072 B
    float* Umat  = (float*)(ws + 37879808);       // 16*8 f32       =      512 B
    char*  W1s   = ws + 37880320;                 // 256x16384 bf16 =  8388608 B
    char*  W2s   = ws + 46268928;                 // 256x256 bf16   =   131072 B
    short* W4h   = (short*)(ws + 46400000);       // 256x32 bf16    =    16384 B
    short* W4l   = (short*)(ws + 46416384);       // 256x32 bf16    =    16384 B
    short* W5h   = (short*)(ws + 46432768);       // 128x256 bf16   =    65536 B
    short* W5l   = (short*)(ws + 46498304);       // 128x256 bf16   =    65536 B

    convW<<<4193, 256, 0, stream>>>(W1, W2, W4, W5, qp,
                                    W1s, W2s, W4h, W4l, W5h, W5l, Umat);
    gemm1<<<256, 512, 0, stream>>>(img, W1s, part);
    gemm2<<<64, 512, 0, stream>>>(part, W2s, b1, b2, h2);
    qsim2<<<B_SZ / 4, 256, 0, stream>>>(h2, W3, b3, Umat, qfbuf);
    head_mfma<<<B_SZ / 64, 256, 0, stream>>>(qfbuf, cid, emb,
                                             W4h, W4l, b4, W5h, W5l, b5,
                                             W6, b6, (float*)d_out);
}